// Round 12
// baseline (6052.630 us; speedup 1.0000x reference)
//
#include <hip/hip_runtime.h>
#include <stdint.h>
#include <math.h>

typedef unsigned long long u64;
typedef unsigned int u32;

// ---------------- workspace layout (bytes) ----------------
static const size_t OFF_CTL  = 0;          // [0]=u64 kstar, [12]=u32 compact count
static const size_t OFF_DOTS = 1024;       // 16384*54*4 (f32 head dots)
static const size_t OFF_WCV  = 3539968;    // 589824*4 (conv weights f32 [tap][ic][oc])
static const size_t OFF_XD   = 5899264;    // 16384*256*4 (conv1 out f32, HWC)
static const size_t OFF_BOX  = 22676480;   // 147456*16 (float4 boxes)
static const size_t OFF_KEYS = 25035776;   // 147456*8
static const size_t OFF_CKEY = 26215424;   // 6144*8
static const size_t OFF_CIDX = 26264576;   // 6144*4
static const size_t OFF_TB   = 26289152;   // 6000*16 (float4)
static const size_t OFF_TSC  = 26385152;   // 6000*4  end ~26.4 MB

// XLA-CPU / Eigen / Cephes f32 exp (FMA form). Inputs here are |x| < 30, so
// the clamp paths are irrelevant; what matters is the Cody-Waite split and
// the p0..p5 Horner-FMA chain — reproduces XLA's exp bit pattern.
__device__ __forceinline__ float exp_xla(float x) {
    float m = floorf(__fmaf_rn(x, 1.44269504088896341f, 0.5f));
    float r = __fmaf_rn(m, -0.693359375f, x);
    r = __fmaf_rn(m, 2.12194440e-4f, r);
    float r2 = r * r;
    float p = 1.9875691500e-4f;
    p = __fmaf_rn(p, r, 1.3981999507e-3f);
    p = __fmaf_rn(p, r, 8.3334519073e-3f);
    p = __fmaf_rn(p, r, 4.1665795894e-2f);
    p = __fmaf_rn(p, r, 1.6666665459e-1f);
    p = __fmaf_rn(p, r, 5.0000001201e-1f);
    p = __fmaf_rn(p, r2, r);
    p = __fadd_rn(p, 1.0f);
    int mi = (int)m;                         // scale by 2^m exactly
    return p * __int_as_float((mi + 127) << 23);
}

// ---------------- weight prep: rpn_w [oc][ic][tap] -> f32 [tap][ic][oc] ------
__global__ void prep_wcv(const float* __restrict__ rpn_w, float* __restrict__ wcv) {
    int t = blockIdx.x * 256 + threadIdx.x;
    if (t >= 589824) return;
    int tap = t / 65536, rem = t % 65536, ic = rem / 256, oc = rem % 256;
    wcv[t] = rpn_w[oc * 2304 + ic * 9 + tap];
}

// ---------------- conv3x3: ONE continuous f32 FMA chain, k=(ky,kx,ic) --------
// Mirrors XLA-CPU (NHWC canonicalized, Eigen im2col GEMM): per output element
// a single accumulator FMA chain over k = tap*256+ic ascending. Out-of-image
// taps contribute fma(0,w,acc) == acc exactly, matching im2col zero padding.
// grid (8,8,64): 16x16 pixels, 4 ocs/block; feat read direct from L1/L2.
__global__ __launch_bounds__(256, 1) void conv3x3(const float* __restrict__ feat,
                                                  const float* __restrict__ wcv,
                                                  const float* __restrict__ rpn_b,
                                                  float* __restrict__ xd) {
    const int tx = threadIdx.x & 15, ty = threadIdx.x >> 4;
    const int gx = blockIdx.x * 16 + tx, gy = blockIdx.y * 16 + ty;
    const int oc0 = blockIdx.z * 4;
    float a0 = 0.f, a1 = 0.f, a2 = 0.f, a3 = 0.f;
#pragma unroll
    for (int tap = 0; tap < 9; ++tap) {           // k-major: tap (ky,kx)
        const int yy = gy + tap / 3 - 1, xx = gx + tap % 3 - 1;
        const bool in = (yy >= 0 && yy < 128 && xx >= 0 && xx < 128);
        const float* fp = feat + yy * 128 + xx;
        const float* wp = wcv + tap * 65536 + oc0;  // [ic][oc], wave-uniform
        for (int ic = 0; ic < 256; ++ic) {        // k-minor: ic ascending
            float f = in ? fp[ic * 16384] : 0.f;
            const float* w = wp + ic * 256;
            a0 = __fmaf_rn(f, w[0], a0);
            a1 = __fmaf_rn(f, w[1], a1);
            a2 = __fmaf_rn(f, w[2], a2);
            a3 = __fmaf_rn(f, w[3], a3);
        }
    }
    float* outp = xd + (size_t)(gy * 128 + gx) * 256 + oc0;
    float v0 = __fadd_rn(a0, rpn_b[oc0 + 0]);
    float v1 = __fadd_rn(a1, rpn_b[oc0 + 1]);
    float v2 = __fadd_rn(a2, rpn_b[oc0 + 2]);
    float v3 = __fadd_rn(a3, rpn_b[oc0 + 3]);
    outp[0] = v0 > 0.f ? v0 : 0.f;
    outp[1] = v1 > 0.f ? v1 : 0.f;
    outp[2] = v2 > 0.f ? v2 : 0.f;
    outp[3] = v3 > 0.f ? v3 : 0.f;
}

// ---------------- heads: 1x1 convs = GEMM, k=ic sequential f32 FMA -----------
__global__ __launch_bounds__(256, 1) void heads_seq(const float* __restrict__ xd,
                                                    const float* __restrict__ cls_w,
                                                    const float* __restrict__ box_w,
                                                    float* __restrict__ dots) {
    __shared__ float sX[4][257];  // +1 pad
    const int tid = threadIdx.x;
    const int pix0 = blockIdx.x * 4;
    for (int idx = tid; idx < 1024; idx += 256)
        sX[idx >> 8][idx & 255] = xd[(size_t)(pix0 + (idx >> 8)) * 256 + (idx & 255)];
    __syncthreads();
    if (tid < 216) {
        const int pl = tid / 54, o = tid % 54;
        const float* wr = (o < 18) ? (cls_w + o * 256) : (box_w + (o - 18) * 256);
        float acc = 0.f;
        for (int ic = 0; ic < 256; ++ic)
            acc = __fmaf_rn(sX[pl][ic], wr[ic], acc);
        dots[(size_t)(pix0 + pl) * 54 + o] = acc;     // raw dot (biases are 0)
    }
}

// ---------------- decode: stepwise-F32 softmax + box decode, XLA exp ---------
__global__ __launch_bounds__(256, 1) void decode(const float* __restrict__ dots,
                                                 const float* __restrict__ cls_b,
                                                 const float* __restrict__ box_b,
                                                 float4* __restrict__ boxes,
                                                 u64* __restrict__ keys) {
    const int pix = blockIdx.x * 256 + threadIdx.x;
    if (pix >= 16384) return;
    const float* dt = dots + (size_t)pix * 54;
    float d[54];
#pragma unroll
    for (int i = 0; i < 54; ++i)
        d[i] = __fadd_rn(dt[i], (i < 18 ? cls_b[i] : box_b[i - 18]));
    float m = d[0];
#pragma unroll
    for (int i = 1; i < 18; ++i) m = fmaxf(m, d[i]);
    float e[18];
#pragma unroll
    for (int i = 0; i < 18; ++i) e[i] = exp_xla(__fsub_rn(d[i], m));
    float s = e[0];  // XLA reduce over innermost 18: sequential
#pragma unroll
    for (int i = 1; i < 18; ++i) s = __fadd_rn(s, e[i]);
    const int y = pix >> 7, x = pix & 127;
    const float shx = (float)(x * 32), shy = (float)(y * 32);
    const float AW[9] = {368.f, 736.f, 1472.f, 256.f, 512.f, 1024.f, 176.f, 352.f, 704.f};
    const float AH[9] = {192.f, 384.f, 768.f, 256.f, 512.f, 1024.f, 352.f, 704.f, 1408.f};
#pragma unroll
    for (int a = 0; a < 9; ++a) {
        float score = e[9 + a] / s;
        float wa = AW[a], ha = AH[a];
        float cxa = __fadd_rn(shx, 7.5f), cya = __fadd_rn(shy, 7.5f);  // exact
        float dx = d[18 + 4 * a], dyy = d[19 + 4 * a];
        float dw = d[20 + 4 * a], dh = d[21 + 4 * a];
        float cx = __fadd_rn(__fmul_rn(dx, wa), cxa);
        float cy = __fadd_rn(__fmul_rn(dyy, ha), cya);
        float pw = __fmul_rn(wa, exp_xla(dw));
        float ph = __fmul_rn(ha, exp_xla(dh));
        float hx = __fmul_rn(0.5f, pw), hy = __fmul_rn(0.5f, ph);
        float x1 = fminf(fmaxf(__fsub_rn(cx, hx), 0.f), 4095.f);
        float y1 = fminf(fmaxf(__fsub_rn(cy, hy), 0.f), 4095.f);
        float x2 = fminf(fmaxf(__fadd_rn(cx, hx), 0.f), 4095.f);
        float y2 = fminf(fmaxf(__fadd_rn(cy, hy), 0.f), 4095.f);
        float vw = __fadd_rn(__fsub_rn(x2, x1), 1.0f);
        float vh = __fadd_rn(__fsub_rn(y2, y1), 1.0f);
        bool valid = (vw >= 16.0f) && (vh >= 16.0f);
        int i = pix * 9 + a;
        boxes[i] = make_float4(x1, y1, x2, y2);
        u64 k;
        if (valid) {  // ascending key == descending f32 score; idx tie-break
            u32 b = __float_as_uint(score);
            k = ((u64)(u32)~(b | 0x80000000u) << 32) | (u32)i;
        } else {
            k = (0xFFFFFFFFULL << 32) | (u32)i;
        }
        keys[i] = k;
    }
}

// ---------------- single-block radix select of rank-6000 key -----------------
__global__ __launch_bounds__(1024, 1) void select_kstar(const u64* __restrict__ keys,
                                                        u64* __restrict__ kstar) {
    __shared__ u32 hist[256];
    __shared__ u64 s_prefix;
    __shared__ u32 s_target;
    const int t = threadIdx.x;
    if (t == 0) { s_prefix = 0ULL; s_target = 6000u; }
    __syncthreads();
    for (int p = 0; p < 8; ++p) {
        if (t < 256) hist[t] = 0;
        __syncthreads();
        const int shift = 56 - 8 * p;
        const u64 pref = s_prefix;
        for (int i = t; i < 147456; i += 1024) {
            u64 k = keys[i];
            bool match = (p == 0) || ((k >> (shift + 8)) == pref);
            if (match) atomicAdd(&hist[(u32)(k >> shift) & 0xFFu], 1u);
        }
        __syncthreads();
        if (t == 0) {
            u32 target = s_target, cum = 0; int d = 0;
            for (int b = 0; b < 256; ++b) {
                u32 c = hist[b];
                if (cum + c >= target) { d = b; break; }
                cum += c;
            }
            s_prefix = (s_prefix << 8) | (u64)d;
            s_target = target - cum;
        }
        __syncthreads();
    }
    if (t == 0) *kstar = s_prefix;
}

__global__ void compact(const u64* __restrict__ keys, const u64* __restrict__ kstar,
                        u32* count, u64* __restrict__ ckey, u32* __restrict__ cidx) {
    int i = blockIdx.x * 256 + threadIdx.x;
    if (i >= 147456) return;
    u64 k = keys[i];
    if (k <= *kstar) {  // unique keys -> exactly 6000 pass
        u32 pos = atomicAdd(count, 1u);
        if (pos < 6144) { ckey[pos] = k; cidx[pos] = (u32)(k & 0xFFFFFFFFu); }
    }
}

__global__ void init_tbsc(float4* __restrict__ tb, float* __restrict__ tsc) {
    int r = blockIdx.x * 256 + threadIdx.x;
    if (r >= 6000) return;
    tb[r] = make_float4(0.f, 0.f, 0.f, 0.f);
    tsc[r] = -__builtin_inff();
}

// ---------------- exact rank (keys unique) + gather sorted top-6000 ----------
__global__ __launch_bounds__(256) void rank_scatter(const u64* __restrict__ ckey,
                                                    const u32* __restrict__ cidx,
                                                    const u32* __restrict__ count,
                                                    const float4* __restrict__ boxes,
                                                    float4* __restrict__ tb,
                                                    float* __restrict__ tsc) {
    __shared__ u64 LK[6144];
    int N = (int)*count; if (N > 6144) N = 6144;
    for (int i = threadIdx.x; i < N; i += 256) LK[i] = ckey[i];
    __syncthreads();
    int e = blockIdx.x * 256 + threadIdx.x;
    if (e >= N) return;
    u64 myK = LK[e];
    u32 myI = cidx[e];
    int rank = 0;
    for (int c = 0; c < N; ++c) rank += (LK[c] < myK);
    if (rank < 6000) {
        tb[rank] = boxes[myI];
        u32 hi = (u32)(myK >> 32);
        tsc[rank] = (hi == 0xFFFFFFFFu) ? -__builtin_inff()
                                        : __uint_as_float(~hi & 0x7FFFFFFFu);
    }
}

// ---------------- reference-literal greedy NMS, all-F32, no fma --------------
__global__ __launch_bounds__(1024, 1) void nms(const float4* __restrict__ tb,
                                               const float* __restrict__ tsc,
                                               float* __restrict__ out) {
    __shared__ unsigned char s_alive[6016];
    __shared__ float s_best[1024];
    __shared__ int s_idx[1024];
    __shared__ float s_bj[4];
    const int t = threadIdx.x;
    const float NEG = -__builtin_inff();
    for (int r = t; r < 6000; r += 1024)
        s_alive[r] = (tsc[r] > NEG) ? 1 : 0;  // alive0 = isfinite(top_scores)
    __syncthreads();
    for (int k = 0; k < 1000; ++k) {
        float bs = NEG; int bi = 0x7FFFFFFF;
        for (int r = t; r < 6000; r += 1024) {
            float s = s_alive[r] ? tsc[r] : NEG;
            if (s > bs) { bs = s; bi = r; }  // ascending r => first occurrence
        }
        s_best[t] = bs; s_idx[t] = bi;
        __syncthreads();
        for (int w = 512; w > 0; w >>= 1) {
            if (t < w) {
                float os = s_best[t + w]; int oi = s_idx[t + w];
                if (os > s_best[t] || (os == s_best[t] && oi < s_idx[t])) {
                    s_best[t] = os; s_idx[t] = oi;
                }
            }
            __syncthreads();
        }
        const bool ok = s_best[0] > NEG;
        const int j = ok ? s_idx[0] : 0;
        if (t == 0) {
            float4 bj = tb[j];
            s_bj[0] = bj.x; s_bj[1] = bj.y; s_bj[2] = bj.z; s_bj[3] = bj.w;
            if (ok) {
                out[k * 5 + 1] = bj.x;
                out[k * 5 + 2] = bj.y;
                out[k * 5 + 3] = bj.z;
                out[k * 5 + 4] = bj.w;
            }
        }
        __syncthreads();
        const float jx1 = s_bj[0], jy1 = s_bj[1], jx2 = s_bj[2], jy2 = s_bj[3];
        const float areaJ = __fmul_rn(__fadd_rn(__fsub_rn(jx2, jx1), 1.0f),
                                      __fadd_rn(__fsub_rn(jy2, jy1), 1.0f));
        for (int r = t; r < 6000; r += 1024) {
            if (!s_alive[r]) continue;
            float4 b = tb[r];
            float ar = __fmul_rn(__fadd_rn(__fsub_rn(b.z, b.x), 1.0f),
                                 __fadd_rn(__fsub_rn(b.w, b.y), 1.0f));
            float xx1 = fmaxf(jx1, b.x), yy1 = fmaxf(jy1, b.y);
            float xx2 = fminf(jx2, b.z), yy2 = fminf(jy2, b.w);
            float ww = fmaxf(__fadd_rn(__fsub_rn(xx2, xx1), 1.0f), 0.0f);
            float hh = fmaxf(__fadd_rn(__fsub_rn(yy2, yy1), 1.0f), 0.0f);
            float inter = __fmul_rn(ww, hh);
            float uni = __fsub_rn(__fadd_rn(areaJ, ar), inter);
            float iou = inter / uni;
            if (iou > 0.7f) s_alive[r] = 0;
        }
        __syncthreads();
    }
}

// ---------------- host ----------------
extern "C" void kernel_launch(void* const* d_in, const int* in_sizes, int n_in,
                              void* d_out, int out_size, void* d_ws, size_t ws_size,
                              hipStream_t stream) {
    const float *feat = nullptr, *rpn_w = nullptr, *rpn_b = nullptr;
    const float *cls_w = nullptr, *cls_b = nullptr, *box_w = nullptr, *box_b = nullptr;
    for (int i = 0; i < n_in; ++i) {
        switch (in_sizes[i]) {
            case 4194304: feat  = (const float*)d_in[i]; break;
            case 589824:  rpn_w = (const float*)d_in[i]; break;
            case 256:     rpn_b = (const float*)d_in[i]; break;
            case 4608:    cls_w = (const float*)d_in[i]; break;
            case 18:      cls_b = (const float*)d_in[i]; break;
            case 9216:    box_w = (const float*)d_in[i]; break;
            case 36:      box_b = (const float*)d_in[i]; break;
            default: break;  // image dims hardcoded (4096)
        }
    }

    char* w = (char*)d_ws;
    u64* kstar     = (u64*)(w + OFF_CTL);
    u32* ctlCount  = (u32*)(w + OFF_CTL + 12);
    float* dots    = (float*)(w + OFF_DOTS);
    float* wcv     = (float*)(w + OFF_WCV);
    float* xd      = (float*)(w + OFF_XD);
    float4* boxes  = (float4*)(w + OFF_BOX);
    u64* keys      = (u64*)(w + OFF_KEYS);
    u64* ckey      = (u64*)(w + OFF_CKEY);
    u32* cidx      = (u32*)(w + OFF_CIDX);
    float4* tb     = (float4*)(w + OFF_TB);
    float* tsc     = (float*)(w + OFF_TSC);

    hipMemsetAsync(d_ws, 0, 1024, stream);                      // ctl only
    hipMemsetAsync(d_out, 0, (size_t)out_size * sizeof(float), stream);

    prep_wcv<<<2304, 256, 0, stream>>>(rpn_w, wcv);
    conv3x3<<<dim3(8, 8, 64), 256, 0, stream>>>(feat, wcv, rpn_b, xd);
    heads_seq<<<4096, 256, 0, stream>>>(xd, cls_w, box_w, dots);
    decode<<<64, 256, 0, stream>>>(dots, cls_b, box_b, boxes, keys);
    select_kstar<<<1, 1024, 0, stream>>>(keys, kstar);
    compact<<<576, 256, 0, stream>>>(keys, kstar, ctlCount, ckey, cidx);
    init_tbsc<<<24, 256, 0, stream>>>(tb, tsc);
    rank_scatter<<<24, 256, 0, stream>>>(ckey, cidx, ctlCount, boxes, tb, tsc);
    nms<<<1, 1024, 0, stream>>>(tb, tsc, (float*)d_out);
}

// Round 13
// 1614.076 us; speedup vs baseline: 3.7499x; 3.7499x over previous
//
#include <hip/hip_runtime.h>
#include <stdint.h>
#include <math.h>

typedef unsigned long long u64;
typedef unsigned int u32;

// ---------------- workspace layout (bytes) ----------------
static const size_t OFF_CTL   = 0;          // [0]=u64 prefix/kstar, [8]=u32 target, [12]=u32 count
static const size_t OFF_HIST  = 1024;       // 4 * 65536 * 4 = 1 MB
static const size_t OFF_DOTS  = 1049600;    // 16384*54*4
static const size_t OFF_WCV   = 4588544;    // 589824*4  [tap][ic][oc]
static const size_t OFF_XD    = 6947840;    // 16384*256*4 (conv out f32, HWC)
static const size_t OFF_BOX   = 23725056;   // 147456*16 (float4)
static const size_t OFF_KEYS  = 26084352;   // 147456*8
static const size_t OFF_CKEY  = 27264000;   // 6144*8
static const size_t OFF_CIDX  = 27313152;   // 6144*4
static const size_t OFF_TB    = 27337728;   // 6000*16
static const size_t OFF_TSC   = 27433728;   // 6000*4
static const size_t OFF_ALIVE = 27458048;   // 128*8
static const size_t OFF_MASK  = 27459072;   // 6000*96*8 = 4608000  end ~32.1 MB

// XLA-CPU / Eigen / Cephes f32 exp (FMA form) — bit-matches the np reference.
__device__ __forceinline__ float exp_xla(float x) {
    float m = floorf(__fmaf_rn(x, 1.44269504088896341f, 0.5f));
    float r = __fmaf_rn(m, -0.693359375f, x);
    r = __fmaf_rn(m, 2.12194440e-4f, r);
    float r2 = r * r;
    float p = 1.9875691500e-4f;
    p = __fmaf_rn(p, r, 1.3981999507e-3f);
    p = __fmaf_rn(p, r, 8.3334519073e-3f);
    p = __fmaf_rn(p, r, 4.1665795894e-2f);
    p = __fmaf_rn(p, r, 1.6666665459e-1f);
    p = __fmaf_rn(p, r, 5.0000001201e-1f);
    p = __fmaf_rn(p, r2, r);
    p = __fadd_rn(p, 1.0f);
    int mi = (int)m;
    return p * __int_as_float((mi + 127) << 23);
}

// ---------------- weight prep: rpn_w [oc][ic][tap] -> f32 [tap][ic][oc] ------
__global__ void prep_wcv(const float* __restrict__ rpn_w, float* __restrict__ wcv) {
    int t = blockIdx.x * 256 + threadIdx.x;
    if (t >= 589824) return;
    int tap = t / 65536, rem = t % 65536, ic = rem / 256, oc = rem % 256;
    wcv[t] = rpn_w[oc * 2304 + ic * 9 + tap];
}

// ---------------- conv3x3: single f32 FMA chain k=(tap,ic); 16 oc/thread -----
// Same arithmetic as the passing round-12 kernel (fma(0,w,acc)==acc for pads);
// weights staged per-tap in LDS (broadcast reads), 4x less feat re-read.
__global__ __launch_bounds__(256, 1) void conv3x3(const float* __restrict__ feat,
                                                  const float* __restrict__ wcv,
                                                  const float* __restrict__ rpn_b,
                                                  float* __restrict__ xd) {
    __shared__ float sW[4096];  // [ic][16 oc] for current tap
    const int tx = threadIdx.x & 15, ty = threadIdx.x >> 4;
    const int gx = blockIdx.x * 16 + tx, gy = blockIdx.y * 16 + ty;
    const int oc0 = blockIdx.z * 16;
    float acc[16];
#pragma unroll
    for (int o = 0; o < 16; ++o) acc[o] = 0.f;
#pragma unroll
    for (int tap = 0; tap < 9; ++tap) {           // k-major: tap (ky,kx)
        __syncthreads();
        for (int idx = threadIdx.x; idx < 4096; idx += 256) {
            int ic = idx >> 4, oc = idx & 15;
            sW[idx] = wcv[tap * 65536 + ic * 256 + oc0 + oc];
        }
        __syncthreads();
        const int yy = gy + tap / 3 - 1, xx = gx + tap % 3 - 1;
        const bool in = (yy >= 0 && yy < 128 && xx >= 0 && xx < 128);
        const float* fp = feat + yy * 128 + xx;
        for (int ic = 0; ic < 256; ++ic) {        // k-minor: ic ascending
            float f = in ? fp[ic * 16384] : 0.f;
            const float* w = sW + ic * 16;        // wave-uniform -> broadcast
#pragma unroll
            for (int o = 0; o < 16; ++o) acc[o] = __fmaf_rn(f, w[o], acc[o]);
        }
    }
    float* outp = xd + (size_t)(gy * 128 + gx) * 256 + oc0;
#pragma unroll
    for (int o = 0; o < 16; ++o) {
        float v = __fadd_rn(acc[o], rpn_b[oc0 + o]);
        outp[o] = v > 0.f ? v : 0.f;
    }
}

// ---------------- heads: 1x1 convs, k=ic sequential f32 FMA ------------------
__global__ __launch_bounds__(256, 1) void heads_seq(const float* __restrict__ xd,
                                                    const float* __restrict__ cls_w,
                                                    const float* __restrict__ box_w,
                                                    float* __restrict__ dots) {
    __shared__ float sX[4][257];
    const int tid = threadIdx.x;
    const int pix0 = blockIdx.x * 4;
    for (int idx = tid; idx < 1024; idx += 256)
        sX[idx >> 8][idx & 255] = xd[(size_t)(pix0 + (idx >> 8)) * 256 + (idx & 255)];
    __syncthreads();
    if (tid < 216) {
        const int pl = tid / 54, o = tid % 54;
        const float* wr = (o < 18) ? (cls_w + o * 256) : (box_w + (o - 18) * 256);
        float acc = 0.f;
        for (int ic = 0; ic < 256; ++ic)
            acc = __fmaf_rn(sX[pl][ic], wr[ic], acc);
        dots[(size_t)(pix0 + pl) * 54 + o] = acc;
    }
}

// ---------------- decode: stepwise-F32 softmax + box decode, XLA exp ---------
__global__ __launch_bounds__(256, 1) void decode(const float* __restrict__ dots,
                                                 const float* __restrict__ cls_b,
                                                 const float* __restrict__ box_b,
                                                 float4* __restrict__ boxes,
                                                 u64* __restrict__ keys) {
    const int pix = blockIdx.x * 256 + threadIdx.x;
    if (pix >= 16384) return;
    const float* dt = dots + (size_t)pix * 54;
    float d[54];
#pragma unroll
    for (int i = 0; i < 54; ++i)
        d[i] = __fadd_rn(dt[i], (i < 18 ? cls_b[i] : box_b[i - 18]));
    float m = d[0];
#pragma unroll
    for (int i = 1; i < 18; ++i) m = fmaxf(m, d[i]);
    float e[18];
#pragma unroll
    for (int i = 0; i < 18; ++i) e[i] = exp_xla(__fsub_rn(d[i], m));
    float s = e[0];
#pragma unroll
    for (int i = 1; i < 18; ++i) s = __fadd_rn(s, e[i]);
    const int y = pix >> 7, x = pix & 127;
    const float shx = (float)(x * 32), shy = (float)(y * 32);
    const float AW[9] = {368.f, 736.f, 1472.f, 256.f, 512.f, 1024.f, 176.f, 352.f, 704.f};
    const float AH[9] = {192.f, 384.f, 768.f, 256.f, 512.f, 1024.f, 352.f, 704.f, 1408.f};
#pragma unroll
    for (int a = 0; a < 9; ++a) {
        float score = e[9 + a] / s;
        float wa = AW[a], ha = AH[a];
        float cxa = __fadd_rn(shx, 7.5f), cya = __fadd_rn(shy, 7.5f);
        float dx = d[18 + 4 * a], dyy = d[19 + 4 * a];
        float dw = d[20 + 4 * a], dh = d[21 + 4 * a];
        float cx = __fadd_rn(__fmul_rn(dx, wa), cxa);
        float cy = __fadd_rn(__fmul_rn(dyy, ha), cya);
        float pw = __fmul_rn(wa, exp_xla(dw));
        float ph = __fmul_rn(ha, exp_xla(dh));
        float hx = __fmul_rn(0.5f, pw), hy = __fmul_rn(0.5f, ph);
        float x1 = fminf(fmaxf(__fsub_rn(cx, hx), 0.f), 4095.f);
        float y1 = fminf(fmaxf(__fsub_rn(cy, hy), 0.f), 4095.f);
        float x2 = fminf(fmaxf(__fadd_rn(cx, hx), 0.f), 4095.f);
        float y2 = fminf(fmaxf(__fadd_rn(cy, hy), 0.f), 4095.f);
        float vw = __fadd_rn(__fsub_rn(x2, x1), 1.0f);
        float vh = __fadd_rn(__fsub_rn(y2, y1), 1.0f);
        bool valid = (vw >= 16.0f) && (vh >= 16.0f);
        int i = pix * 9 + a;
        boxes[i] = make_float4(x1, y1, x2, y2);
        u64 k;
        if (valid) {
            u32 b = __float_as_uint(score);
            k = ((u64)(u32)~(b | 0x80000000u) << 32) | (u32)i;
        } else {
            k = (0xFFFFFFFFULL << 32) | (u32)i;
        }
        keys[i] = k;
    }
}

// ---------------- parallel radix select: 4 passes of 16 bits -----------------
__global__ void hist16(const u64* __restrict__ keys, u32* __restrict__ hist,
                       const u64* __restrict__ pfx, int pass) {
    int i = blockIdx.x * 256 + threadIdx.x;
    if (i >= 147456) return;
    u64 k = keys[i];
    int shift = 48 - 16 * pass;
    bool match = (pass == 0) || ((k >> (shift + 16)) == *pfx);
    if (match) atomicAdd(&hist[(u32)(k >> shift) & 0xFFFFu], 1u);
}

__global__ __launch_bounds__(1024) void scan16(const u32* __restrict__ hist,
                                               u64* pfx, u32* tgt, int pass) {
    __shared__ u32 part[1024];
    __shared__ u32 excl[1024];
    const int t = threadIdx.x;
    // read control BEFORE any write (race-free: barrier below)
    u32 target = (pass == 0) ? 6000u : *tgt;
    u64 p0 = (pass == 0) ? 0ULL : *pfx;
    __syncthreads();
    u32 sum = 0;
    for (int b = 0; b < 64; ++b) sum += hist[t * 64 + b];
    part[t] = sum;
    __syncthreads();
    if (t == 0) {
        u32 run = 0;
        for (int i = 0; i < 1024; ++i) { excl[i] = run; run += part[i]; }
    }
    __syncthreads();
    u32 before = excl[t];
    if (before < target && target <= before + part[t]) {   // unique winner
        u32 cum = before;
        int d = 0; u32 nb = before;
        for (int b = 0; b < 64; ++b) {
            u32 c = hist[t * 64 + b];
            if (cum + c >= target) { d = t * 64 + b; nb = cum; break; }
            cum += c;
        }
        *pfx = (p0 << 16) | (u64)d;
        *tgt = target - nb;
    }
}

__global__ void compact(const u64* __restrict__ keys, const u64* __restrict__ kstar,
                        u32* count, u64* __restrict__ ckey, u32* __restrict__ cidx) {
    int i = blockIdx.x * 256 + threadIdx.x;
    if (i >= 147456) return;
    u64 k = keys[i];
    if (k <= *kstar) {  // unique keys -> exactly 6000 pass
        u32 pos = atomicAdd(count, 1u);
        if (pos < 6144) { ckey[pos] = k; cidx[pos] = (u32)(k & 0xFFFFFFFFu); }
    }
}

__global__ void init_tbsc(float4* __restrict__ tb, float* __restrict__ tsc) {
    int r = blockIdx.x * 256 + threadIdx.x;
    if (r >= 6000) return;
    tb[r] = make_float4(0.f, 0.f, 0.f, 0.f);
    tsc[r] = -__builtin_inff();
}

// ---------------- exact rank (keys unique) + gather sorted top-6000 ----------
__global__ __launch_bounds__(256) void rank_scatter(const u64* __restrict__ ckey,
                                                    const u32* __restrict__ cidx,
                                                    const u32* __restrict__ count,
                                                    const float4* __restrict__ boxes,
                                                    float4* __restrict__ tb,
                                                    float* __restrict__ tsc) {
    __shared__ u64 LK[6144];
    int N = (int)*count; if (N > 6144) N = 6144;
    for (int i = threadIdx.x; i < N; i += 256) LK[i] = ckey[i];
    __syncthreads();
    int e = blockIdx.x * 256 + threadIdx.x;
    if (e >= N) return;
    u64 myK = LK[e];
    u32 myI = cidx[e];
    int rank = 0;
    for (int c = 0; c < N; ++c) rank += (LK[c] < myK);
    if (rank < 6000) {
        tb[rank] = boxes[myI];
        u32 hi = (u32)(myK >> 32);
        tsc[rank] = (hi == 0xFFFFFFFFu) ? -__builtin_inff()
                                        : __uint_as_float(~hi & 0x7FFFFFFFu);
    }
}

// ---------------- alive bitmask init (94 words used, 96 written) -------------
__global__ void alive_init(const float* __restrict__ tsc, u64* __restrict__ alive0) {
    int r = blockIdx.x * 256 + threadIdx.x;  // 24*256 = 6144 -> words 0..95
    bool a = false;
    if (r < 6000) a = tsc[r] > -__builtin_inff();
    u64 b = __ballot(a);
    if ((threadIdx.x & 63) == 0) alive0[r >> 6] = b;
}

// ---------------- suppression bitmask: m[j][i] = iou(tb[j],tb[i]) > 0.7 ------
// Exact same f32 ops as the (passing) round-12 NMS / the ref's iou matrix.
__global__ __launch_bounds__(256) void nms_mask(const float4* __restrict__ tb,
                                                u64* __restrict__ mask) {
    int tid = blockIdx.x * 256 + threadIdx.x;
    if (tid >= 6000 * 94) return;
    int j = tid / 94, w = tid % 94;
    float4 bj = tb[j];
    float arJ = __fmul_rn(__fadd_rn(__fsub_rn(bj.z, bj.x), 1.0f),
                          __fadd_rn(__fsub_rn(bj.w, bj.y), 1.0f));
    u64 m = 0;
    int base = w * 64;
#pragma unroll 4
    for (int b = 0; b < 64; ++b) {
        int i = base + b;
        if (i >= 6000) break;
        float4 bi = tb[i];
        float arI = __fmul_rn(__fadd_rn(__fsub_rn(bi.z, bi.x), 1.0f),
                              __fadd_rn(__fsub_rn(bi.w, bi.y), 1.0f));
        float xx1 = fmaxf(bj.x, bi.x), yy1 = fmaxf(bj.y, bi.y);
        float xx2 = fminf(bj.z, bi.z), yy2 = fminf(bj.w, bi.w);
        float ww = fmaxf(__fadd_rn(__fsub_rn(xx2, xx1), 1.0f), 0.0f);
        float hh = fmaxf(__fadd_rn(__fsub_rn(yy2, yy1), 1.0f), 0.0f);
        float inter = __fmul_rn(ww, hh);
        float uni = __fsub_rn(__fadd_rn(arJ, arI), inter);
        float iou = inter / uni;
        if (iou > 0.7f) m |= (1ULL << b);
    }
    mask[(size_t)j * 96 + w] = m;
}

// ---------------- sequential NMS scan: one wave, zero barriers ---------------
// tb sorted desc (unique keys, idx tie-break) => argmax(alive) == first alive.
__global__ __launch_bounds__(64, 1) void nms_seq(const u64* __restrict__ alive0,
                                                 const u64* __restrict__ mask,
                                                 const float4* __restrict__ tb,
                                                 float* __restrict__ out) {
    const int lane = threadIdx.x;
    u64 wl = alive0[lane];                      // words 0..63
    u64 wh = (lane < 30) ? alive0[64 + lane] : 0ULL;  // words 64..93
    for (int k = 0; k < 1000; ++k) {
        u64 blo = __ballot(wl != 0ULL);
        u64 bhi = __ballot(wh != 0ULL);
        int wi; u64 word;
        if (blo) {
            int l = __ffsll(blo) - 1;
            wi = l; word = __shfl(wl, l);
        } else if (bhi) {
            int l = __ffsll(bhi) - 1;
            wi = 64 + l; word = __shfl(wh, l);
        } else {
            break;  // exhausted: remaining rows stay zero (ref: selv=0)
        }
        int j = wi * 64 + (__ffsll(word) - 1);
        if (lane == 0) {
            float4 bj = tb[j];
            out[k * 5 + 1] = bj.x;
            out[k * 5 + 2] = bj.y;
            out[k * 5 + 3] = bj.z;
            out[k * 5 + 4] = bj.w;
        }
        const u64* row = mask + (size_t)j * 96;
        wl &= ~row[lane];                        // kills j itself (iou==1)
        if (lane < 30) wh &= ~row[64 + lane];
    }
}

// ---------------- host ----------------
extern "C" void kernel_launch(void* const* d_in, const int* in_sizes, int n_in,
                              void* d_out, int out_size, void* d_ws, size_t ws_size,
                              hipStream_t stream) {
    const float *feat = nullptr, *rpn_w = nullptr, *rpn_b = nullptr;
    const float *cls_w = nullptr, *cls_b = nullptr, *box_w = nullptr, *box_b = nullptr;
    for (int i = 0; i < n_in; ++i) {
        switch (in_sizes[i]) {
            case 4194304: feat  = (const float*)d_in[i]; break;
            case 589824:  rpn_w = (const float*)d_in[i]; break;
            case 256:     rpn_b = (const float*)d_in[i]; break;
            case 4608:    cls_w = (const float*)d_in[i]; break;
            case 18:      cls_b = (const float*)d_in[i]; break;
            case 9216:    box_w = (const float*)d_in[i]; break;
            case 36:      box_b = (const float*)d_in[i]; break;
            default: break;  // image dims hardcoded (4096)
        }
    }

    char* w = (char*)d_ws;
    u64* pfx       = (u64*)(w + OFF_CTL);
    u32* tgt       = (u32*)(w + OFF_CTL + 8);
    u32* ctlCount  = (u32*)(w + OFF_CTL + 12);
    u32* hist      = (u32*)(w + OFF_HIST);
    float* dots    = (float*)(w + OFF_DOTS);
    float* wcv     = (float*)(w + OFF_WCV);
    float* xd      = (float*)(w + OFF_XD);
    float4* boxes  = (float4*)(w + OFF_BOX);
    u64* keys      = (u64*)(w + OFF_KEYS);
    u64* ckey      = (u64*)(w + OFF_CKEY);
    u32* cidx      = (u32*)(w + OFF_CIDX);
    float4* tb     = (float4*)(w + OFF_TB);
    float* tsc     = (float*)(w + OFF_TSC);
    u64* alive0    = (u64*)(w + OFF_ALIVE);
    u64* mask      = (u64*)(w + OFF_MASK);

    hipMemsetAsync(d_ws, 0, OFF_HIST + 4 * 65536 * 4, stream);  // ctl + hists
    hipMemsetAsync(d_out, 0, (size_t)out_size * sizeof(float), stream);

    prep_wcv<<<2304, 256, 0, stream>>>(rpn_w, wcv);
    conv3x3<<<dim3(8, 8, 16), 256, 0, stream>>>(feat, wcv, rpn_b, xd);
    heads_seq<<<4096, 256, 0, stream>>>(xd, cls_w, box_w, dots);
    decode<<<64, 256, 0, stream>>>(dots, cls_b, box_b, boxes, keys);
    for (int p = 0; p < 4; ++p) {
        hist16<<<576, 256, 0, stream>>>(keys, hist + p * 65536, pfx, p);
        scan16<<<1, 1024, 0, stream>>>(hist + p * 65536, pfx, tgt, p);
    }
    compact<<<576, 256, 0, stream>>>(keys, pfx, ctlCount, ckey, cidx);
    init_tbsc<<<24, 256, 0, stream>>>(tb, tsc);
    rank_scatter<<<24, 256, 0, stream>>>(ckey, cidx, ctlCount, boxes, tb, tsc);
    alive_init<<<24, 256, 0, stream>>>(tsc, alive0);
    nms_mask<<<2204, 256, 0, stream>>>(tb, mask);
    nms_seq<<<1, 64, 0, stream>>>(alive0, mask, tb, (float*)d_out);
}

// Round 14
// 1579.652 us; speedup vs baseline: 3.8316x; 1.0218x over previous
//
#include <hip/hip_runtime.h>
#include <stdint.h>
#include <math.h>

typedef unsigned long long u64;
typedef unsigned int u32;

// ---------------- workspace layout (bytes) ----------------
static const size_t OFF_CTL   = 0;          // [0]=u64 prefix/kstar, [8]=u32 target, [12]=u32 count
static const size_t OFF_HIST  = 1024;       // 8 passes * 256 * 4 = 8 KB
static const size_t OFF_DOTS  = 1049600;    // 16384*54*4
static const size_t OFF_WCV   = 4588544;    // 589824*4  [tap][ic][oc]
static const size_t OFF_XD    = 6947840;    // 16384*256*4 (conv out f32, HWC)
static const size_t OFF_BOX   = 23725056;   // 147456*16 (float4)
static const size_t OFF_KEYS  = 26084352;   // 147456*8
static const size_t OFF_CKEY  = 27264000;   // 6144*8
static const size_t OFF_CIDX  = 27313152;   // 6144*4
static const size_t OFF_TB    = 27337728;   // 6000*16
static const size_t OFF_TSC   = 27433728;   // 6000*4
static const size_t OFF_ALIVE = 27458048;   // 128*8
static const size_t OFF_MASK  = 27459072;   // 6000*96*8 = 4608000  end ~32.1 MB

// XLA-CPU / Eigen / Cephes f32 exp (FMA form) — bit-matches the np reference.
__device__ __forceinline__ float exp_xla(float x) {
    float m = floorf(__fmaf_rn(x, 1.44269504088896341f, 0.5f));
    float r = __fmaf_rn(m, -0.693359375f, x);
    r = __fmaf_rn(m, 2.12194440e-4f, r);
    float r2 = r * r;
    float p = 1.9875691500e-4f;
    p = __fmaf_rn(p, r, 1.3981999507e-3f);
    p = __fmaf_rn(p, r, 8.3334519073e-3f);
    p = __fmaf_rn(p, r, 4.1665795894e-2f);
    p = __fmaf_rn(p, r, 1.6666665459e-1f);
    p = __fmaf_rn(p, r, 5.0000001201e-1f);
    p = __fmaf_rn(p, r2, r);
    p = __fadd_rn(p, 1.0f);
    int mi = (int)m;
    return p * __int_as_float((mi + 127) << 23);
}

// ---------------- weight prep: rpn_w [oc][ic][tap] -> f32 [tap][ic][oc] ------
__global__ void prep_wcv(const float* __restrict__ rpn_w, float* __restrict__ wcv) {
    int t = blockIdx.x * 256 + threadIdx.x;
    if (t >= 589824) return;
    int tap = t / 65536, rem = t % 65536, ic = rem / 256, oc = rem % 256;
    wcv[t] = rpn_w[oc * 2304 + ic * 9 + tap];
}

// ---------------- conv3x3: single f32 FMA chain k=(tap,ic); 32 oc/thread -----
// Same per-oc chain arithmetic as the passing round-12/13 kernels (oc-blocking
// never reorders a chain; fma(0,w,acc)==acc for pads). Weights read through a
// wave-uniform pointer -> scalar loads (no LDS in inner loop). 1D grid of 512:
// id = tile + 64*ocb  =>  all 8 oc-blocks of a tile share id%8 (same XCD L2).
__global__ __launch_bounds__(256, 1) void conv3x3(const float* __restrict__ feat,
                                                  const float* __restrict__ wcv,
                                                  const float* __restrict__ rpn_b,
                                                  float* __restrict__ xd) {
    const int blk = blockIdx.x;
    const int ocb = blk >> 6, t = blk & 63;
    const int gx = (t & 7) * 16 + (threadIdx.x & 15);
    const int gy = (t >> 3) * 16 + (threadIdx.x >> 4);
    const int oc0 = ocb * 32;
    float acc[32];
#pragma unroll
    for (int o = 0; o < 32; ++o) acc[o] = 0.f;
#pragma unroll
    for (int tap = 0; tap < 9; ++tap) {           // k-major: tap (ky,kx)
        const int yy = gy + tap / 3 - 1, xx = gx + tap % 3 - 1;
        const bool in = (yy >= 0 && yy < 128 && xx >= 0 && xx < 128);
        const float* fp = feat + yy * 128 + xx;
        const float* wp = wcv + tap * 65536 + oc0;   // wave-uniform -> s_load
        for (int ic = 0; ic < 256; ++ic) {        // k-minor: ic ascending
            float f = in ? fp[ic * 16384] : 0.f;
            const float* w = wp + ic * 256;
#pragma unroll
            for (int o = 0; o < 32; ++o) acc[o] = __fmaf_rn(f, w[o], acc[o]);
        }
    }
    float* outp = xd + (size_t)(gy * 128 + gx) * 256 + oc0;
#pragma unroll
    for (int o = 0; o < 32; ++o) {
        float v = __fadd_rn(acc[o], rpn_b[oc0 + o]);
        outp[o] = v > 0.f ? v : 0.f;
    }
}

// ---------------- heads: 1x1 convs, k=ic sequential f32 FMA ------------------
__global__ __launch_bounds__(256, 1) void heads_seq(const float* __restrict__ xd,
                                                    const float* __restrict__ cls_w,
                                                    const float* __restrict__ box_w,
                                                    float* __restrict__ dots) {
    __shared__ float sX[4][257];
    const int tid = threadIdx.x;
    const int pix0 = blockIdx.x * 4;
    for (int idx = tid; idx < 1024; idx += 256)
        sX[idx >> 8][idx & 255] = xd[(size_t)(pix0 + (idx >> 8)) * 256 + (idx & 255)];
    __syncthreads();
    if (tid < 216) {
        const int pl = tid / 54, o = tid % 54;
        const float* wr = (o < 18) ? (cls_w + o * 256) : (box_w + (o - 18) * 256);
        float acc = 0.f;
        for (int ic = 0; ic < 256; ++ic)
            acc = __fmaf_rn(sX[pl][ic], wr[ic], acc);
        dots[(size_t)(pix0 + pl) * 54 + o] = acc;
    }
}

// ---------------- decode: stepwise-F32 softmax + box decode, XLA exp ---------
__global__ __launch_bounds__(256, 1) void decode(const float* __restrict__ dots,
                                                 const float* __restrict__ cls_b,
                                                 const float* __restrict__ box_b,
                                                 float4* __restrict__ boxes,
                                                 u64* __restrict__ keys) {
    const int pix = blockIdx.x * 256 + threadIdx.x;
    if (pix >= 16384) return;
    const float* dt = dots + (size_t)pix * 54;
    float d[54];
#pragma unroll
    for (int i = 0; i < 54; ++i)
        d[i] = __fadd_rn(dt[i], (i < 18 ? cls_b[i] : box_b[i - 18]));
    float m = d[0];
#pragma unroll
    for (int i = 1; i < 18; ++i) m = fmaxf(m, d[i]);
    float e[18];
#pragma unroll
    for (int i = 0; i < 18; ++i) e[i] = exp_xla(__fsub_rn(d[i], m));
    float s = e[0];
#pragma unroll
    for (int i = 1; i < 18; ++i) s = __fadd_rn(s, e[i]);
    const int y = pix >> 7, x = pix & 127;
    const float shx = (float)(x * 32), shy = (float)(y * 32);
    const float AW[9] = {368.f, 736.f, 1472.f, 256.f, 512.f, 1024.f, 176.f, 352.f, 704.f};
    const float AH[9] = {192.f, 384.f, 768.f, 256.f, 512.f, 1024.f, 352.f, 704.f, 1408.f};
#pragma unroll
    for (int a = 0; a < 9; ++a) {
        float score = e[9 + a] / s;
        float wa = AW[a], ha = AH[a];
        float cxa = __fadd_rn(shx, 7.5f), cya = __fadd_rn(shy, 7.5f);
        float dx = d[18 + 4 * a], dyy = d[19 + 4 * a];
        float dw = d[20 + 4 * a], dh = d[21 + 4 * a];
        float cx = __fadd_rn(__fmul_rn(dx, wa), cxa);
        float cy = __fadd_rn(__fmul_rn(dyy, ha), cya);
        float pw = __fmul_rn(wa, exp_xla(dw));
        float ph = __fmul_rn(ha, exp_xla(dh));
        float hx = __fmul_rn(0.5f, pw), hy = __fmul_rn(0.5f, ph);
        float x1 = fminf(fmaxf(__fsub_rn(cx, hx), 0.f), 4095.f);
        float y1 = fminf(fmaxf(__fsub_rn(cy, hy), 0.f), 4095.f);
        float x2 = fminf(fmaxf(__fadd_rn(cx, hx), 0.f), 4095.f);
        float y2 = fminf(fmaxf(__fadd_rn(cy, hy), 0.f), 4095.f);
        float vw = __fadd_rn(__fsub_rn(x2, x1), 1.0f);
        float vh = __fadd_rn(__fsub_rn(y2, y1), 1.0f);
        bool valid = (vw >= 16.0f) && (vh >= 16.0f);
        int i = pix * 9 + a;
        boxes[i] = make_float4(x1, y1, x2, y2);
        u64 k;
        if (valid) {
            u32 b = __float_as_uint(score);
            k = ((u64)(u32)~(b | 0x80000000u) << 32) | (u32)i;
        } else {
            k = (0xFFFFFFFFULL << 32) | (u32)i;
        }
        keys[i] = k;
    }
}

// ---------------- radix select: 8 passes of 8 bits, LDS histograms -----------
__global__ __launch_bounds__(256) void hist8(const u64* __restrict__ keys,
                                             u32* __restrict__ ghist,
                                             const u64* __restrict__ pfx, int pass) {
    __shared__ u32 lh[256];
    lh[threadIdx.x] = 0;
    __syncthreads();
    const u64 pref = *pfx;  // pass 0: unused (memset 0)
    const int shift = 56 - 8 * pass;
    for (int i = blockIdx.x * 256 + threadIdx.x; i < 147456; i += 64 * 256) {
        u64 k = keys[i];
        bool match = (pass == 0) || ((k >> (shift + 8)) == pref);
        if (match) atomicAdd(&lh[(u32)(k >> shift) & 0xFFu], 1u);
    }
    __syncthreads();
    if (lh[threadIdx.x]) atomicAdd(&ghist[threadIdx.x], lh[threadIdx.x]);
}

__global__ __launch_bounds__(256) void scan8(const u32* __restrict__ ghist,
                                             u64* pfx, u32* tgt, int pass) {
    __shared__ u32 h[256];
    __shared__ u32 incl[256];
    const int t = threadIdx.x;
    u32 target = (pass == 0) ? 6000u : *tgt;   // read before winner's write
    u64 p0 = (pass == 0) ? 0ULL : *pfx;
    h[t] = ghist[t];
    incl[t] = h[t];
    __syncthreads();
    for (int off = 1; off < 256; off <<= 1) {
        u32 v = (t >= off) ? incl[t - off] : 0u;
        __syncthreads();
        incl[t] += v;
        __syncthreads();
    }
    u32 before = incl[t] - h[t];
    if (before < target && target <= incl[t]) {   // unique winner
        *pfx = (p0 << 8) | (u64)t;
        *tgt = target - before;
    }
}

__global__ void compact(const u64* __restrict__ keys, const u64* __restrict__ kstar,
                        u32* count, u64* __restrict__ ckey, u32* __restrict__ cidx) {
    int i = blockIdx.x * 256 + threadIdx.x;
    if (i >= 147456) return;
    u64 k = keys[i];
    if (k <= *kstar) {  // unique keys -> exactly 6000 pass
        u32 pos = atomicAdd(count, 1u);
        if (pos < 6144) { ckey[pos] = k; cidx[pos] = (u32)(k & 0xFFFFFFFFu); }
    }
}

__global__ void init_tbsc(float4* __restrict__ tb, float* __restrict__ tsc) {
    int r = blockIdx.x * 256 + threadIdx.x;
    if (r >= 6000) return;
    tb[r] = make_float4(0.f, 0.f, 0.f, 0.f);
    tsc[r] = -__builtin_inff();
}

// ---------------- exact rank (keys unique) + gather sorted top-6000 ----------
__global__ __launch_bounds__(256) void rank_scatter(const u64* __restrict__ ckey,
                                                    const u32* __restrict__ cidx,
                                                    const u32* __restrict__ count,
                                                    const float4* __restrict__ boxes,
                                                    float4* __restrict__ tb,
                                                    float* __restrict__ tsc) {
    __shared__ u64 LK[6144];
    int N = (int)*count; if (N > 6144) N = 6144;
    for (int i = threadIdx.x; i < N; i += 256) LK[i] = ckey[i];
    __syncthreads();
    int e = blockIdx.x * 256 + threadIdx.x;
    if (e >= N) return;
    u64 myK = LK[e];
    u32 myI = cidx[e];
    int rank = 0;
    for (int c = 0; c < N; ++c) rank += (LK[c] < myK);
    if (rank < 6000) {
        tb[rank] = boxes[myI];
        u32 hi = (u32)(myK >> 32);
        tsc[rank] = (hi == 0xFFFFFFFFu) ? -__builtin_inff()
                                        : __uint_as_float(~hi & 0x7FFFFFFFu);
    }
}

// ---------------- alive bitmask init (94 words used, 96 written) -------------
__global__ void alive_init(const float* __restrict__ tsc, u64* __restrict__ alive0) {
    int r = blockIdx.x * 256 + threadIdx.x;  // 24*256 = 6144 -> words 0..95
    bool a = false;
    if (r < 6000) a = tsc[r] > -__builtin_inff();
    u64 b = __ballot(a);
    if ((threadIdx.x & 63) == 0) alive0[r >> 6] = b;
}

// ---------------- suppression bitmask: m[j][i] = iou(tb[j],tb[i]) > 0.7 ------
__global__ __launch_bounds__(256) void nms_mask(const float4* __restrict__ tb,
                                                u64* __restrict__ mask) {
    int tid = blockIdx.x * 256 + threadIdx.x;
    if (tid >= 6000 * 94) return;
    int j = tid / 94, w = tid % 94;
    float4 bj = tb[j];
    float arJ = __fmul_rn(__fadd_rn(__fsub_rn(bj.z, bj.x), 1.0f),
                          __fadd_rn(__fsub_rn(bj.w, bj.y), 1.0f));
    u64 m = 0;
    int base = w * 64;
#pragma unroll 4
    for (int b = 0; b < 64; ++b) {
        int i = base + b;
        if (i >= 6000) break;
        float4 bi = tb[i];
        float arI = __fmul_rn(__fadd_rn(__fsub_rn(bi.z, bi.x), 1.0f),
                              __fadd_rn(__fsub_rn(bi.w, bi.y), 1.0f));
        float xx1 = fmaxf(bj.x, bi.x), yy1 = fmaxf(bj.y, bi.y);
        float xx2 = fminf(bj.z, bi.z), yy2 = fminf(bj.w, bi.w);
        float ww = fmaxf(__fadd_rn(__fsub_rn(xx2, xx1), 1.0f), 0.0f);
        float hh = fmaxf(__fadd_rn(__fsub_rn(yy2, yy1), 1.0f), 0.0f);
        float inter = __fmul_rn(ww, hh);
        float uni = __fsub_rn(__fadd_rn(arJ, arI), inter);
        float iou = inter / uni;
        if (iou > 0.7f) m |= (1ULL << b);
    }
    mask[(size_t)j * 96 + w] = m;
}

// ---------------- sequential NMS scan: one wave, zero barriers ---------------
__global__ __launch_bounds__(64, 1) void nms_seq(const u64* __restrict__ alive0,
                                                 const u64* __restrict__ mask,
                                                 const float4* __restrict__ tb,
                                                 float* __restrict__ out) {
    const int lane = threadIdx.x;
    u64 wl = alive0[lane];                            // words 0..63
    u64 wh = (lane < 30) ? alive0[64 + lane] : 0ULL;  // words 64..93
    for (int k = 0; k < 1000; ++k) {
        u64 blo = __ballot(wl != 0ULL);
        u64 bhi = __ballot(wh != 0ULL);
        int wi; u64 word;
        if (blo) {
            int l = __ffsll(blo) - 1;
            wi = l; word = __shfl(wl, l);
        } else if (bhi) {
            int l = __ffsll(bhi) - 1;
            wi = 64 + l; word = __shfl(wh, l);
        } else {
            break;  // exhausted: remaining rows stay zero (ref: selv=0)
        }
        int j = wi * 64 + (__ffsll(word) - 1);
        if (lane == 0) {
            float4 bj = tb[j];
            out[k * 5 + 1] = bj.x;
            out[k * 5 + 2] = bj.y;
            out[k * 5 + 3] = bj.z;
            out[k * 5 + 4] = bj.w;
        }
        const u64* row = mask + (size_t)j * 96;
        wl &= ~row[lane];                        // kills j itself (iou==1)
        if (lane < 30) wh &= ~row[64 + lane];
    }
}

// ---------------- host ----------------
extern "C" void kernel_launch(void* const* d_in, const int* in_sizes, int n_in,
                              void* d_out, int out_size, void* d_ws, size_t ws_size,
                              hipStream_t stream) {
    const float *feat = nullptr, *rpn_w = nullptr, *rpn_b = nullptr;
    const float *cls_w = nullptr, *cls_b = nullptr, *box_w = nullptr, *box_b = nullptr;
    for (int i = 0; i < n_in; ++i) {
        switch (in_sizes[i]) {
            case 4194304: feat  = (const float*)d_in[i]; break;
            case 589824:  rpn_w = (const float*)d_in[i]; break;
            case 256:     rpn_b = (const float*)d_in[i]; break;
            case 4608:    cls_w = (const float*)d_in[i]; break;
            case 18:      cls_b = (const float*)d_in[i]; break;
            case 9216:    box_w = (const float*)d_in[i]; break;
            case 36:      box_b = (const float*)d_in[i]; break;
            default: break;  // image dims hardcoded (4096)
        }
    }

    char* w = (char*)d_ws;
    u64* pfx       = (u64*)(w + OFF_CTL);
    u32* tgt       = (u32*)(w + OFF_CTL + 8);
    u32* ctlCount  = (u32*)(w + OFF_CTL + 12);
    u32* hist      = (u32*)(w + OFF_HIST);
    float* dots    = (float*)(w + OFF_DOTS);
    float* wcv     = (float*)(w + OFF_WCV);
    float* xd      = (float*)(w + OFF_XD);
    float4* boxes  = (float4*)(w + OFF_BOX);
    u64* keys      = (u64*)(w + OFF_KEYS);
    u64* ckey      = (u64*)(w + OFF_CKEY);
    u32* cidx      = (u32*)(w + OFF_CIDX);
    float4* tb     = (float4*)(w + OFF_TB);
    float* tsc     = (float*)(w + OFF_TSC);
    u64* alive0    = (u64*)(w + OFF_ALIVE);
    u64* mask      = (u64*)(w + OFF_MASK);

    hipMemsetAsync(d_ws, 0, OFF_HIST + 8 * 256 * 4, stream);  // ctl + 8 hists
    hipMemsetAsync(d_out, 0, (size_t)out_size * sizeof(float), stream);

    prep_wcv<<<2304, 256, 0, stream>>>(rpn_w, wcv);
    conv3x3<<<512, 256, 0, stream>>>(feat, wcv, rpn_b, xd);
    heads_seq<<<4096, 256, 0, stream>>>(xd, cls_w, box_w, dots);
    decode<<<64, 256, 0, stream>>>(dots, cls_b, box_b, boxes, keys);
    for (int p = 0; p < 8; ++p) {
        hist8<<<64, 256, 0, stream>>>(keys, hist + p * 256, pfx, p);
        scan8<<<1, 256, 0, stream>>>(hist + p * 256, pfx, tgt, p);
    }
    compact<<<576, 256, 0, stream>>>(keys, pfx, ctlCount, ckey, cidx);
    init_tbsc<<<24, 256, 0, stream>>>(tb, tsc);
    rank_scatter<<<24, 256, 0, stream>>>(ckey, cidx, ctlCount, boxes, tb, tsc);
    alive_init<<<24, 256, 0, stream>>>(tsc, alive0);
    nms_mask<<<2204, 256, 0, stream>>>(tb, mask);
    nms_seq<<<1, 64, 0, stream>>>(alive0, mask, tb, (float*)d_out);
}